// Round 12
// baseline (158.809 us; speedup 1.0000x reference)
//
#include <hip/hip_runtime.h>
#include <hip/hip_bf16.h>

// Problem constants (N=2, C=256, H=W=64) — float32 I/O per reference.
#define NBATCH 2
#define CCH    256
#define LLEN   4096      // H*W
#define NGROUP 8
#define CPG    32        // C / NGROUP
#define NHEAD  4
#define HD     64        // C / NHEAD
#define GEPS   1e-5f
// q pre-scale: hd^-0.5 * log2(e); scores feed v_exp_f32 (2^x) directly.
#define QSCALE 0.18033688011112042f

// Generic MFMA fragment tiling (16x16x32 bf16): a [R x 256ch] tensor is stored
// as tiles [r16][c32] of 512 ushorts; element (r, c) sits at
// tile*512 + ((r&15) + 16*((c>>3)&3))*8 + (c&7). Same frag serves A and B roles.

typedef short bf16x8 __attribute__((ext_vector_type(8)));
typedef float f32x4  __attribute__((ext_vector_type(4)));

__device__ __forceinline__ unsigned short f2b(float f) {
  unsigned u = __float_as_uint(f);
  u += 0x7FFFu + ((u >> 16) & 1u);
  return (unsigned short)(u >> 16);
}
__device__ __forceinline__ unsigned pack2bf(float a, float b) {
  __hip_bfloat162 h = __float22bfloat162_rn(make_float2(a, b));
  union { __hip_bfloat162 h; unsigned u; } c;
  c.h = h;
  return c.u;
}
__device__ __forceinline__ float exp2_(float x) {
#if __has_builtin(__builtin_amdgcn_exp2f)
  return __builtin_amdgcn_exp2f(x);
#else
  return exp2f(x);
#endif
}

// ------- setup: wcvt->tiled W (blocks 0..255) | gn partials (256..383) | mask (384..415) -------
__global__ __launch_bounds__(256) void setup_kernel(
    const float* __restrict__ qw, const float* __restrict__ kw,
    const float* __restrict__ vw, const float* __restrict__ pw,
    const float* __restrict__ qb, const float* __restrict__ kb,
    const float* __restrict__ vb, const float* __restrict__ pb,
    const float* __restrict__ x, const int* __restrict__ mask,
    unsigned short* __restrict__ w16, float* __restrict__ bias_ws,
    float* __restrict__ part, float* __restrict__ out2) {
  __shared__ float rs[4], rss[4];
  const int b = blockIdx.x;
  const int t = threadIdx.x;
  if (b < 256) {
    const int idx = b * 256 + t;               // float4 units; 65536 total
    const int m = idx >> 14;
    const int rem = idx & 16383;
    const int cout = rem >> 6;                 // 0..255
    const int ch4 = (rem & 63) << 2;           // 0..252
    const float* src[4] = {qw, kw, vw, pw};
    const float sc = (m == 0) ? QSCALE : 1.0f;
    const float4 v = ((const float4*)src[m])[(size_t)cout * 64 + (ch4 >> 2)];
    unsigned short* dst = w16 +
        ((size_t)(m * 16 + (cout >> 4)) * 8 + (ch4 >> 5)) * 512 +
        ((cout & 15) + 16 * ((ch4 >> 3) & 3)) * 8 + (ch4 & 7);
    dst[0] = f2b(v.x * sc); dst[1] = f2b(v.y * sc);
    dst[2] = f2b(v.z * sc); dst[3] = f2b(v.w * sc);
    if (b == 0) {
      bias_ws[t]       = qb[t] * QSCALE;
      bias_ws[256 + t] = kb[t];
      bias_ws[512 + t] = vb[t];
      bias_ws[768 + t] = pb[t];
    }
  } else if (b < 384) {
    const int sb = b - 256;
    const int gidx = sb >> 3, sub = sb & 7;
    const float4* xp = (const float4*)(x + (size_t)gidx * (CPG * LLEN)) + (size_t)sub * 4096;
    float s = 0.f, ss = 0.f;
    for (int i = t; i < 4096; i += 256) {
      const float4 v = xp[i];
      s += v.x + v.y + v.z + v.w;
      ss = fmaf(v.x, v.x, ss);
      ss = fmaf(v.y, v.y, ss);
      ss = fmaf(v.z, v.z, ss);
      ss = fmaf(v.w, v.w, ss);
    }
#pragma unroll
    for (int off = 32; off; off >>= 1) {
      s  += __shfl_down(s, off);
      ss += __shfl_down(ss, off);
    }
    if ((t & 63) == 0) { rs[t >> 6] = s; rss[t >> 6] = ss; }
    __syncthreads();
    if (t == 0) {
      part[sb * 2 + 0] = rs[0] + rs[1] + rs[2] + rs[3];
      part[sb * 2 + 1] = rss[0] + rss[1] + rss[2] + rss[3];
    }
  } else {
    const int i = (b - 384) * 256 + t;
    out2[i] = (float)mask[i];
  }
}

// ------- GroupNorm apply + transpose -> bf16 xn, fragment-tiled -------
__global__ __launch_bounds__(256) void gn_apply_kernel(const float* __restrict__ x,
                                                       const float* __restrict__ w,
                                                       const float* __restrict__ b,
                                                       const float* __restrict__ part,
                                                       unsigned short* __restrict__ xn16) {
  const int l0 = blockIdx.x * 32, c0 = blockIdx.y * 32, n = blockIdx.z;
  const int g16 = n * 8 + (c0 >> 5);
  float s = 0.f, ss = 0.f;
#pragma unroll
  for (int i = 0; i < 8; i++) {
    s  += part[(g16 * 8 + i) * 2 + 0];
    ss += part[(g16 * 8 + i) * 2 + 1];
  }
  const float inv_cnt = 1.0f / (float)(CPG * LLEN);
  const float mu = s * inv_cnt;
  const float rsg = rsqrtf(ss * inv_cnt - mu * mu + GEPS);
  __shared__ float tile[32][33];
  const int tx = threadIdx.x & 31, ty = threadIdx.x >> 5;
#pragma unroll
  for (int i = 0; i < 4; i++) {
    const int c = c0 + ty + 8 * i;
    const float wc = w[c], bc = b[c];
    const float v = x[((size_t)n * CCH + c) * LLEN + l0 + tx];
    tile[ty + 8 * i][tx] = (v - mu) * rsg * wc + bc;
  }
  __syncthreads();
  const int c = c0 + tx;
#pragma unroll
  for (int i = 0; i < 4; i++) {
    const int l = l0 + ty + 8 * i;
    const size_t pos = (((size_t)n * 256 + (l >> 4)) * 8 + (c >> 5)) * 512 +
                       ((l & 15) + 16 * ((c >> 3) & 3)) * 8 + (c & 7);
    xn16[pos] = f2b(tile[tx][ty + 8 * i]);
  }
}

// ------- QKV GEMM, LDS-free register MFMA (unchanged from round 11) -------
__global__ __launch_bounds__(256, 4) void qkv_mfma_kernel(
    const unsigned short* __restrict__ xn16,
    const unsigned short* __restrict__ w16,
    const float* __restrict__ bias_ws,
    unsigned short* __restrict__ q16,
    unsigned short* __restrict__ k16,
    unsigned short* __restrict__ v16) {
  const int t = threadIdx.x;
  const int lane = t & 63, wv = t >> 6;
  const int col = lane & 15, quad = lane >> 4;
  const int m0 = blockIdx.x * 64;
  const int by = blockIdx.y;
  const int co0 = by * 64;
  const int wsel = blockIdx.z;
  const int n = m0 >> 12;
  const int m16b = (m0 & 4095) >> 4;

  const unsigned short* xnb = xn16 + (size_t)n * (256 * 8 * 512);
  const unsigned short* wb  = w16 + ((size_t)(wsel * 16 + by * 4 + wv) * 8) * 512 + lane * 8;

  f32x4 acc[4];
#pragma unroll
  for (int i = 0; i < 4; i++) acc[i] = {0.f, 0.f, 0.f, 0.f};

#pragma unroll
  for (int kc = 0; kc < 8; kc++) {
    const bf16x8 wf = *(const bf16x8*)(wb + (size_t)kc * 512);
#pragma unroll
    for (int mt = 0; mt < 4; mt++) {
      const bf16x8 xf = *(const bf16x8*)(xnb + ((size_t)(m16b + mt) * 8 + kc) * 512 + lane * 8);
      acc[mt] = (wsel < 2)
          ? __builtin_amdgcn_mfma_f32_16x16x32_bf16(xf, wf, acc[mt], 0, 0, 0)
          : __builtin_amdgcn_mfma_f32_16x16x32_bf16(wf, xf, acc[mt], 0, 0, 0);
    }
  }

  if (wsel < 2) {
    unsigned short* dst = (wsel == 0) ? q16 : k16;
    const float bias = bias_ws[wsel * CCH + co0 + wv * 16 + col];
    const int lquad = (wv * 2 + (col >> 3)) & 3;
    const int j = col & 7;
#pragma unroll
    for (int mt = 0; mt < 4; mt++) {
      const size_t base = ((size_t)(n * 256 + m16b + mt) * 8 + by * 2 + (wv >> 1)) * 512 + j;
#pragma unroll
      for (int r = 0; r < 4; r++)
        dst[base + ((quad * 4 + r) + 16 * lquad) * 8] = f2b(acc[mt][r] + bias);
    }
  } else {
    const int l0 = m0 & 4095;
    const int j = col & 7;
#pragma unroll
    for (int ct = 0; ct < 4; ct++) {
      const size_t base = ((size_t)(n * 128 + (l0 >> 5) + (ct >> 1)) * 16 + by * 4 + wv) * 512 +
                          16 * (((ct & 1) << 1) + (col >> 3)) * 8 + j;
#pragma unroll
      for (int r = 0; r < 4; r++) {
        const int cout = co0 + wv * 16 + quad * 4 + r;
        v16[base + (quad * 4 + r) * 8] = f2b(acc[ct][r] + bias_ws[2 * CCH + cout]);
      }
    }
  }
}

// ------- Flash attention v5: fully-unrolled key loop with ping-pong register
//   buffers; constant-stride addressing; no K/V LDS; in-kernel normalize. -------
__global__ __launch_bounds__(256, 2) void attn_mfma_kernel(
    const unsigned short* __restrict__ q16,   // Q' tiled, pre-scaled
    const unsigned short* __restrict__ k16,   // K' tiled
    const unsigned short* __restrict__ v16,   // V' tiled
    unsigned short* __restrict__ o16) {       // O' tiled (normalized)
  __shared__ __align__(16) unsigned char shraw[20480];
  unsigned short (*pT)[64][40] = (unsigned short (*)[64][40])shraw;   // [wv][qrow][key+pad]
  f32x4 (*red)[4][64] = (f32x4 (*)[4][64])shraw;                      // [srcwv][ct][lane]
  f32x4 (*lred)[64] = (f32x4 (*)[64])(shraw + 16384);                 // [srcwv][lane]
  const int t = threadIdx.x;
  const int lane = t & 63, wv = t >> 6;
  const int col = lane & 15, quad = lane >> 4;
  const int n = blockIdx.y >> 2, h = blockIdx.y & 3;
  const int hc = h * HD;

  const unsigned short* qb = q16 + (size_t)n * (256 * 8 * 512);
  // per-wave constant-stride bases: chunk advances both K' and V' by 16*512
  const unsigned short* kp = k16 + (size_t)n * (256 * 8 * 512) +
                             ((size_t)wv * 64 * 8 + h * 2) * 512 + lane * 8;
  const unsigned short* vp = v16 + (size_t)n * (128 * 16 * 512) +
                             ((size_t)wv * 32 * 16 + h * 4) * 512 + lane * 8;

  // Q B-frags (shared by all waves)
  bf16x8 bq[4][2];
#pragma unroll
  for (int qt = 0; qt < 4; qt++)
#pragma unroll
    for (int ks = 0; ks < 2; ks++)
      bq[qt][ks] = *(const bf16x8*)(qb + ((size_t)(blockIdx.x * 4 + qt) * 8 + h * 2 + ks) * 512 + lane * 8);

  bf16x8 bones;
#pragma unroll
  for (int i = 0; i < 8; i++) bones[i] = (short)0x3F80;   // bf16 1.0

  f32x4 o[4][4], lacc[4];
#pragma unroll
  for (int qt = 0; qt < 4; qt++) {
    lacc[qt] = {0.f, 0.f, 0.f, 0.f};
#pragma unroll
    for (int ct = 0; ct < 4; ct++) o[qt][ct] = {0.f, 0.f, 0.f, 0.f};
  }

  // ping-pong buffers; frag offsets: K (chunk*16 + kt*8 + ks)*512, V (chunk*16 + ct)*512
  bf16x8 ka[2][2][2], bv[2][4];
#pragma unroll
  for (int kt = 0; kt < 2; kt++)
#pragma unroll
    for (int ks = 0; ks < 2; ks++)
      ka[0][kt][ks] = *(const bf16x8*)(kp + (size_t)(kt * 8 + ks) * 512);
#pragma unroll
  for (int ct = 0; ct < 4; ct++)
    bv[0][ct] = *(const bf16x8*)(vp + (size_t)ct * 512);

#pragma unroll
  for (int it = 0; it < 32; it++) {
    const int cur = it & 1, nxt = cur ^ 1;
    const int pf = (it < 31) ? it + 1 : 31;   // tail: redundant reload, harmless
    // prefetch next chunk (issues before compute; ~240cyc compute covers L2 hit)
#pragma unroll
    for (int kt = 0; kt < 2; kt++)
#pragma unroll
      for (int ks = 0; ks < 2; ks++)
        ka[nxt][kt][ks] = *(const bf16x8*)(kp + (size_t)(pf * 16 + kt * 8 + ks) * 512);
#pragma unroll
    for (int ct = 0; ct < 4; ct++)
      bv[nxt][ct] = *(const bf16x8*)(vp + (size_t)(pf * 16 + ct) * 512);

    // S^T = K·Q^T; p = 2^s; pack to wave-private pT
#pragma unroll
    for (int kt = 0; kt < 2; kt++)
#pragma unroll
      for (int qt = 0; qt < 4; qt++) {
        f32x4 s = {0.f, 0.f, 0.f, 0.f};
        s = __builtin_amdgcn_mfma_f32_16x16x32_bf16(ka[cur][kt][0], bq[qt][0], s, 0, 0, 0);
        s = __builtin_amdgcn_mfma_f32_16x16x32_bf16(ka[cur][kt][1], bq[qt][1], s, 0, 0, 0);
        uint2 w;
        w.x = pack2bf(exp2_(s[0]), exp2_(s[1]));
        w.y = pack2bf(exp2_(s[2]), exp2_(s[3]));
        *(uint2*)&pT[wv][qt * 16 + col][kt * 16 + quad * 4] = w;
      }
    // PV + denominators
#pragma unroll
    for (int qt = 0; qt < 4; qt++) {
      const bf16x8 pa = *(const bf16x8*)&pT[wv][qt * 16 + col][quad * 8];
      lacc[qt] = __builtin_amdgcn_mfma_f32_16x16x32_bf16(pa, bones, lacc[qt], 0, 0, 0);
#pragma unroll
      for (int ct = 0; ct < 4; ct++)
        o[qt][ct] = __builtin_amdgcn_mfma_f32_16x16x32_bf16(pa, bv[cur][ct], o[qt][ct], 0, 0, 0);
    }
  }

  // ---- merge across 4 waves, normalize, store O' tiled ----
  const int cch = hc + wv * 16 + col;
  const int lquad16 = 16 * ((cch >> 3) & 3);
  const size_t ctile = cch >> 5;
#pragma unroll
  for (int qt = 0; qt < 4; qt++) {
    __syncthreads();
#pragma unroll
    for (int ct = 0; ct < 4; ct++) red[wv][ct][lane] = o[qt][ct];
    lred[wv][lane] = lacc[qt];
    __syncthreads();
    f32x4 os = red[0][wv][lane];
    os += red[1][wv][lane];
    os += red[2][wv][lane];
    os += red[3][wv][lane];
    f32x4 ls = lred[0][lane];
    ls += lred[1][lane];
    ls += lred[2][lane];
    ls += lred[3][lane];
    const size_t base = (((size_t)n * 256 + blockIdx.x * 4 + qt) * 8 + ctile) * 512 + (cch & 7);
#pragma unroll
    for (int r = 0; r < 4; r++)
      o16[base + ((quad * 4 + r) + lquad16) * 8] = f2b(os[r] / ls[r]);
  }
}

// ------- Proj GEMM, LDS-free register MFMA + bias + residual -> fp32 out [n,c,l] -------
__global__ __launch_bounds__(256, 4) void proj_mfma_kernel(
    const unsigned short* __restrict__ o16,
    const unsigned short* __restrict__ w16,     // tiled weights (pw at tile 48)
    const float* __restrict__ pbias,
    const float* __restrict__ x,
    float* __restrict__ out) {
  const int t = threadIdx.x;
  const int lane = t & 63, wv = t >> 6;
  const int col = lane & 15, quad = lane >> 4;
  const int m0 = blockIdx.x * 64;
  const int by = blockIdx.y;
  const int co0 = by * 64;
  const int n = m0 >> 12, l0 = m0 & 4095;

  const unsigned short* ob = o16 + (size_t)n * (256 * 8 * 512);
  const unsigned short* wb = w16 + ((size_t)(48 + by * 4 + wv) * 8) * 512 + lane * 8;

  f32x4 acc[4];
#pragma unroll
  for (int i = 0; i < 4; i++) acc[i] = {0.f, 0.f, 0.f, 0.f};

#pragma unroll
  for (int kc = 0; kc < 8; kc++) {
    const bf16x8 aw = *(const bf16x8*)(wb + (size_t)kc * 512);
#pragma unroll
    for (int lt = 0; lt < 4; lt++) {
      const bf16x8 bo = *(const bf16x8*)(ob + ((size_t)((l0 >> 4) + lt) * 8 + kc) * 512 + lane * 8);
      acc[lt] = __builtin_amdgcn_mfma_f32_16x16x32_bf16(aw, bo, acc[lt], 0, 0, 0);
    }
  }
#pragma unroll
  for (int lt = 0; lt < 4; lt++)
#pragma unroll
    for (int r = 0; r < 4; r++) {
      const int cout = co0 + wv * 16 + quad * 4 + r;
      const size_t idx = ((size_t)(n * CCH + cout)) * LLEN + l0 + lt * 16 + col;
      out[idx] = acc[lt][r] + pbias[cout] + x[idx];
    }
}

extern "C" void kernel_launch(void* const* d_in, const int* in_sizes, int n_in,
                              void* d_out, int out_size, void* d_ws, size_t ws_size,
                              hipStream_t stream) {
  (void)in_sizes; (void)n_in; (void)out_size; (void)ws_size;
  const float* x      = (const float*)d_in[0];
  const int*   mask   = (const int*)d_in[1];
  const float* norm_w = (const float*)d_in[2];
  const float* norm_b = (const float*)d_in[3];
  const float* q_w    = (const float*)d_in[4];
  const float* q_b    = (const float*)d_in[5];
  const float* k_w    = (const float*)d_in[6];
  const float* k_b    = (const float*)d_in[7];
  const float* v_w    = (const float*)d_in[8];
  const float* v_b    = (const float*)d_in[9];
  const float* p_w    = (const float*)d_in[10];
  const float* p_b    = (const float*)d_in[11];

  const size_t TSZ = (size_t)NBATCH * LLEN * CCH;   // 2097152 elements
  unsigned short* xn16 = (unsigned short*)d_ws;     // TSZ (tiled)
  unsigned short* q16  = xn16 + TSZ;                // tiled
  unsigned short* k16  = q16 + TSZ;                 // tiled
  unsigned short* v16  = k16 + TSZ;                 // tiled
  unsigned short* o16  = v16 + TSZ;                 // tiled
  unsigned short* w16  = o16 + TSZ;                 // 4*65536 (tiled)
  float* bias_ws = (float*)(w16 + 4 * 65536);       // 4*256
  float* part    = bias_ws + 1024;                  // 256
  // total ~21 MB

  float* out  = (float*)d_out;
  float* out2 = out + TSZ;   // mask chunk

  setup_kernel<<<416, 256, 0, stream>>>(q_w, k_w, v_w, p_w, q_b, k_b, v_b, p_b,
                                        x, mask, w16, bias_ws, part, out2);
  gn_apply_kernel<<<dim3(LLEN / 32, CCH / 32, NBATCH), 256, 0, stream>>>(
      x, norm_w, norm_b, part, xn16);
  qkv_mfma_kernel<<<dim3((NBATCH * LLEN) / 64, CCH / 64, 3), 256, 0, stream>>>(
      xn16, w16, bias_ws, q16, k16, v16);
  attn_mfma_kernel<<<dim3(LLEN / 64, NBATCH * NHEAD), 256, 0, stream>>>(
      q16, k16, v16, o16);
  proj_mfma_kernel<<<dim3((NBATCH * LLEN) / 64, CCH / 64), 256, 0, stream>>>(
      o16, w16, bias_ws + 768, x, out);
}